// Round 10
// baseline (304.690 us; speedup 1.0000x reference)
//
#include <hip/hip_runtime.h>
#include <hip/hip_bf16.h>

typedef __hip_bfloat16 bf16;
typedef __attribute__((ext_vector_type(8))) short short8;
typedef __attribute__((ext_vector_type(4))) float f32x4;

#define DEV static __device__ __forceinline__

static constexpr int SEQ = 2048;
static constexpr int DM  = 1024;
static constexpr int NH  = 16;
static constexpr int HD  = 64;
static constexpr int WIN = 2048;
static constexpr int PAD = 1024;   // WIN/2

// async global->LDS, 16B per lane; LDS dest = wave-uniform base + lane*16
DEV void async16(const void* g, void* l) {
  __builtin_amdgcn_global_load_lds(
      (__attribute__((address_space(1))) void*)(g),
      (__attribute__((address_space(3))) void*)(l), 16, 0, 0);
}

// ---------------------------------------------------------------- K0: f32 -> bf16 convert (x, w_qkv, w_proj)
__global__ __launch_bounds__(256) void k_cvt(const float* __restrict__ x,
                                             const float* __restrict__ wq,
                                             const float* __restrict__ wp,
                                             bf16* __restrict__ xb,
                                             bf16* __restrict__ wqb,
                                             bf16* __restrict__ wpb) {
  const int NX = SEQ * DM, NQ = 3 * DM * DM, NP = DM * DM;
  const int tot = (NX + NQ + NP) >> 2;
  const int stride = gridDim.x * 256;
  for (int i = blockIdx.x * 256 + threadIdx.x; i < tot; i += stride) {
    int e = i << 2;
    const float* s; bf16* d; int o;
    if (e < NX)            { s = x;  d = xb;  o = e; }
    else if (e < NX + NQ)  { s = wq; d = wqb; o = e - NX; }
    else                   { s = wp; d = wpb; o = e - NX - NQ; }
    float4 v = *(const float4*)(s + o);
    __align__(8) bf16 t4[4] = {__float2bfloat16(v.x), __float2bfloat16(v.y),
                               __float2bfloat16(v.z), __float2bfloat16(v.w)};
    *(uint2*)(d + o) = *(uint2*)t4;
  }
}

// ---------------------------------------------------------------- shared GEMM core: C[m][n] = sum_k A[m][k]*B[n][k]
DEV void gemm_core(const bf16* __restrict__ A, const bf16* __restrict__ B,
                   int m0, int n0, int K, int tid, bf16* As, bf16* Bs,
                   f32x4 (&acc)[4][4]) {
  const int lane = tid & 63, wid = tid >> 6;
  const int wm = wid >> 1, wn = wid & 1;
  const int l15 = lane & 15, l4 = lane >> 4;
  for (int k0 = 0; k0 < K; k0 += 64) {
    __syncthreads();
    #pragma unroll
    for (int it = 0; it < 4; ++it) {
      int rb = it * 32 + wid * 8;
      int r  = rb + (lane >> 3);
      int c  = (lane & 7) * 8;
      async16(A + (size_t)(m0 + r) * K + k0 + c, As + rb * 64);
      async16(B + (size_t)(n0 + r) * K + k0 + c, Bs + rb * 64);
    }
    asm volatile("s_waitcnt vmcnt(0)" ::: "memory");
    __syncthreads();
    #pragma unroll
    for (int kk = 0; kk < 2; ++kk) {
      short8 a[4], b[4];
      #pragma unroll
      for (int im = 0; im < 4; ++im)
        a[im] = *(const short8*)(As + (wm * 64 + im * 16 + l15) * 64 + kk * 32 + l4 * 8);
      #pragma unroll
      for (int in = 0; in < 4; ++in)
        b[in] = *(const short8*)(Bs + (wn * 64 + in * 16 + l15) * 64 + kk * 32 + l4 * 8);
      #pragma unroll
      for (int im = 0; im < 4; ++im)
        #pragma unroll
        for (int in = 0; in < 4; ++in)
          acc[im][in] = __builtin_amdgcn_mfma_f32_16x16x32_bf16(a[im], b[in], acc[im][in], 0, 0, 0);
    }
  }
}

// ---------------------------------------------------------------- K1: qkv GEMM + scatter to q(scaled)/k/vT
__global__ __launch_bounds__(256) void k_gemm_qkv(const bf16* __restrict__ A,
                                                  const bf16* __restrict__ B,
                                                  const float* __restrict__ bias,
                                                  bf16* __restrict__ qo,
                                                  bf16* __restrict__ ko,
                                                  bf16* __restrict__ vt) {
  __shared__ bf16 As[128 * 64], Bs[128 * 64];
  const int tid = threadIdx.x, lane = tid & 63;
  const int wid = tid >> 6, wm = wid >> 1, wn = wid & 1;
  const int l15 = lane & 15, l4 = lane >> 4;
  const int m0 = blockIdx.x * 128, n0 = blockIdx.y * 128;
  f32x4 acc[4][4] = {};
  gemm_core(A, B, m0, n0, DM, tid, As, Bs, acc);
  #pragma unroll
  for (int im = 0; im < 4; ++im)
    #pragma unroll
    for (int in = 0; in < 4; ++in) {
      int col = n0 + wn * 64 + in * 16 + l15;
      float bval = bias[col];
      int t = col >> 10, h = (col >> 6) & 15, dd = col & 63;
      int row0 = m0 + wm * 64 + im * 16 + l4 * 4;
      if (t == 2) {
        // v transposed directly: vT[h][dd][j], 4 consecutive j -> one 8B store
        __align__(8) bf16 t4[4];
        #pragma unroll
        for (int r = 0; r < 4; ++r)
          t4[r] = __float2bfloat16(acc[im][in][r] + bval);
        *(uint2*)&vt[((size_t)h * HD + dd) * SEQ + row0] = *(uint2*)t4;
      } else {
        #pragma unroll
        for (int r = 0; r < 4; ++r) {
          float v = acc[im][in][r] + bval;
          size_t idx = ((size_t)h * SEQ + row0 + r) * HD + dd;
          // q folded with hd^-0.5 * log2(e) so scores feed exp2 directly
          if (t == 0) qo[idx] = __float2bfloat16(v * 0.18033688011112042f);
          else        ko[idx] = __float2bfloat16(v);
        }
      }
    }
}

// ---------------------------------------------------------------- attn helpers
DEV void stage_kp(const bf16* kbase, int i0, int tt, int lane, bf16* dst) {
  #pragma unroll
  for (int it = 0; it < 4; ++it) {
    int r  = it * 8 + (lane >> 3);
    int cg = lane & 7;
    int jp = i0 + tt * 32 + r;                 // absolute j'
    int krow = jp - PAD;                       // clamp; pad handled analytically
    krow = krow < 0 ? 0 : (krow > SEQ - 1 ? SEQ - 1 : krow);
    int sc = (cg ^ (r & 7)) * 8;               // pre-swizzled global source
    async16(kbase + (size_t)krow * HD + sc, dst + it * 8 * 64);
  }
}

// LDS K -> MFMA, unswapped: sf[fm][fn]: col=j'(l15), row=i(l4*4+r)
DEV void qk_mfma_lds(const bf16* KPb, const short8 (&qf)[2][2], int l15, int l4,
                     f32x4 (&sf)[2][2]) {
  __builtin_amdgcn_s_setprio(1);
  #pragma unroll
  for (int kg = 0; kg < 2; ++kg) {
    short8 kfr[2];
    #pragma unroll
    for (int fn = 0; fn < 2; ++fn) {
      int jl = fn * 16 + l15;
      int pg = (kg * 4 + l4) ^ (jl & 7);
      kfr[fn] = *(const short8*)&KPb[jl * 64 + pg * 8];
    }
    #pragma unroll
    for (int fm = 0; fm < 2; ++fm)
      #pragma unroll
      for (int fn = 0; fn < 2; ++fn)
        sf[fm][fn] = __builtin_amdgcn_mfma_f32_16x16x32_bf16(qf[fm][kg], kfr[fn], sf[fm][fn], 0, 0, 0);
  }
  __builtin_amdgcn_s_setprio(0);
}

DEV int pad_lo(int i0) { int d = PAD - i0; return d <= 0 ? 0 : (d >> 5); }
DEV int pad_hi(int i0) { int t = ((PAD + SEQ - 1 - i0) >> 5) + 1; return t > 65 ? 65 : t; }

// ---------------------------------------------------------------- K2: fused attn — one QK pass, e in registers
// block = (h, i0); 4 chunk-waves. Phase 1: QK+exp -> packed bf16 e regs + row sums.
// LDS sum exchange. Phase 2: normalize from regs, aligned flush, PV. O reduced in LDS.
__global__ __launch_bounds__(256, 2) void k_attn(const bf16* __restrict__ q,
                                                 const bf16* __restrict__ kkk,
                                                 const bf16* __restrict__ vT,
                                                 float* __restrict__ attn,
                                                 bf16* __restrict__ ao) {
  const int h  = blockIdx.x >> 6;
  const int i0 = (blockIdx.x & 63) << 5;
  const int tid = threadIdx.x;
  const int c = tid >> 6;                     // wave = chunk
  const int lane = tid & 63;
  const int l15 = lane & 15, l4 = lane >> 4;
  const int c0 = c * 16;
  const int lo_g = pad_lo(i0), hi_g = pad_hi(i0);

  // 32 KB time-shared: phase 1 = KP staging, phase 2 = JF ring then O-reduce
  __shared__ __align__(16) char Ubuf[32 * 1024];
  __shared__ float sums[4][32];
  bf16*  KP0 = (bf16*)Ubuf + (c * 2 + 0) * 2048;
  bf16*  KP1 = (bf16*)Ubuf + (c * 2 + 1) * 2048;
  float* JFW = (float*)Ubuf + c * 2048;

  short8 qf[2][2];
  #pragma unroll
  for (int fm = 0; fm < 2; ++fm)
    #pragma unroll
    for (int kg = 0; kg < 2; ++kg)
      qf[fm][kg] = *(const short8*)&q[((size_t)h * SEQ + i0 + fm * 16 + l15) * HD + kg * 32 + l4 * 8];

  const bf16* kbase = kkk + (size_t)h * SEQ * HD;
  const bf16* vbase = vT + (size_t)h * HD * SEQ;
  float* abase = attn + (size_t)(h * SEQ + i0) * WIN;

  // ---------------- phase 1: QK + exp2 -> ep regs (bf16 pairs), row sums
  unsigned int ep[17][2][2][2];               // [s][fm][fn][rpair], static idx via full unroll
  float psum[2][4] = {};

  stage_kp(kbase, i0, c0, lane, KP0);         // c0 even -> buf 0
  #pragma unroll
  for (int s = 0; s < 17; ++s) {
    const int tt = c0 + s;
    int nxt = (s < 16) ? tt + 1 : tt;
    stage_kp(kbase, i0, nxt, lane, ((tt + 1) & 1) ? KP1 : KP0);
    asm volatile("s_waitcnt vmcnt(4)" ::: "memory");

    const bool fp = (tt < lo_g) || (tt >= hi_g);     // all-pad tile: score==0 -> e=1
    f32x4 sf[2][2] = {};
    if (!fp) qk_mfma_lds((tt & 1) ? KP1 : KP0, qf, l15, l4, sf);

    const bool allv = (i0 + tt * 32 >= PAD) && (i0 + tt * 32 + 31 < PAD + SEQ);
    #pragma unroll
    for (int fm = 0; fm < 2; ++fm)
      #pragma unroll
      for (int fn = 0; fn < 2; ++fn) {
        const int J0 = tt * 32 + fn * 16 + l15;      // local j'
        const bool padc = fp || (!allv && ((i0 + J0 < PAD) || (i0 + J0 >= PAD + SEQ)));
        #pragma unroll
        for (int p = 0; p < 2; ++p) {
          float e0 = padc ? 1.0f : __builtin_amdgcn_exp2f(sf[fm][fn][2 * p]);
          float e1 = padc ? 1.0f : __builtin_amdgcn_exp2f(sf[fm][fn][2 * p + 1]);
          unsigned lo16 = __bfloat16_as_ushort(__float2bfloat16(e0));
          unsigned hi16 = __bfloat16_as_ushort(__float2bfloat16(e1));
          ep[s][fm][fn][p] = lo16 | (hi16 << 16);
          // row-sum; window mask only matters at tiles 0 and 64
          if (s < 16) {
            if (s == 0 && c == 0) {
              int iloc = fm * 16 + l4 * 4 + 2 * p;
              int j0v = J0 - iloc;
              if ((unsigned)j0v < (unsigned)WIN) psum[fm][2 * p] += e0;
              if ((unsigned)(j0v - 1) < (unsigned)WIN) psum[fm][2 * p + 1] += e1;
            } else {
              psum[fm][2 * p] += e0;
              psum[fm][2 * p + 1] += e1;
            }
          } else if (c == 3) {                       // tile 64: window tail
            int iloc = fm * 16 + l4 * 4 + 2 * p;
            int j0v = J0 - iloc;
            if ((unsigned)j0v < (unsigned)WIN) psum[fm][2 * p] += e0;
            if ((unsigned)(j0v - 1) < (unsigned)WIN) psum[fm][2 * p + 1] += e1;
          }
        }
      }
  }

  // reduce over l15 (16 lanes) and exchange across waves
  #pragma unroll
  for (int fm = 0; fm < 2; ++fm)
    #pragma unroll
    for (int r = 0; r < 4; ++r) {
      float s = psum[fm][r];
      s += __shfl_xor(s, 1); s += __shfl_xor(s, 2);
      s += __shfl_xor(s, 4); s += __shfl_xor(s, 8);
      if (l15 == 0) sums[c][fm * 16 + l4 * 4 + r] = s;
    }
  __syncthreads();                            // sums ready; KP dead -> JF live

  float inv[2][4];
  #pragma unroll
  for (int fm = 0; fm < 2; ++fm)
    #pragma unroll
    for (int r = 0; r < 4; ++r) {
      int row = fm * 16 + l4 * 4 + r;
      inv[fm][r] = __builtin_amdgcn_rcpf(sums[0][row] + sums[1][row] +
                                         sums[2][row] + sums[3][row]);
    }

  // ---------------- phase 2: normalize from regs, rebin, aligned flush, PV
  f32x4 oacc[2][4] = {};
  #pragma unroll
  for (int s = 0; s < 17; ++s) {
    const int tt = c0 + s;
    short8 bv[4];
    if (s > 0) {
      int jb = (tt - 1) * 32;
      #pragma unroll
      for (int nd = 0; nd < 4; ++nd)
        bv[nd] = *(const short8*)&vbase[(size_t)(nd * 16 + l15) * SEQ + jb + l4 * 8];
    }
    // re-bin diagonal tile from registers into j-aligned JF ring
    #pragma unroll
    for (int fm = 0; fm < 2; ++fm)
      #pragma unroll
      for (int fn = 0; fn < 2; ++fn) {
        const int J0 = tt * 32 + fn * 16 + l15;
        #pragma unroll
        for (int p = 0; p < 2; ++p) {
          unsigned u = ep[s][fm][fn][p];
          float v0 = __uint_as_float(u << 16)          * inv[fm][2 * p];
          float v1 = __uint_as_float(u & 0xffff0000u)  * inv[fm][2 * p + 1];
          int row0 = fm * 16 + l4 * 4 + 2 * p;
          int j60 = (J0 - row0) & 63;
          int pg0 = (j60 >> 2) ^ ((row0 & 7) << 1);
          JFW[row0 * 64 + pg0 * 4 + (j60 & 3)] = v0;
          int row1 = row0 + 1;
          int j61 = (J0 - row1) & 63;
          int pg1 = (j61 >> 2) ^ ((row1 & 7) << 1);
          JFW[row1 * 64 + pg1 * 4 + (j61 & 3)] = v1;
        }
      }
    if (s > 0) {
      const int g = (tt - 1) & 1;
      const int Jb = (tt - 1) * 32;
      #pragma unroll
      for (int st = 0; st < 4; ++st) {
        int row = st * 8 + (lane >> 3);
        int c8 = lane & 7;
        int pgrp = (g * 8 + c8) ^ ((row & 7) << 1);
        f32x4 vv = *(const f32x4*)&JFW[row * 64 + pgrp * 4];
        __builtin_nontemporal_store(vv, (f32x4*)(abase + (size_t)row * WIN + Jb + c8 * 4));
      }
      short8 af[2];
      #pragma unroll
      for (int fm = 0; fm < 2; ++fm) {
        int row = fm * 16 + l15;
        int pg0 = (g * 8 + l4 * 2) ^ ((row & 7) << 1);
        const float* p = &JFW[row * 64 + pg0 * 4];
        union { unsigned short u[8]; short8 v; } tmp;
        #pragma unroll
        for (int e = 0; e < 8; ++e)
          tmp.u[e] = __bfloat16_as_ushort(__float2bfloat16(p[e]));
        af[fm] = tmp.v;
      }
      __builtin_amdgcn_s_setprio(1);
      #pragma unroll
      for (int fm = 0; fm < 2; ++fm)
        #pragma unroll
        for (int nd = 0; nd < 4; ++nd)
          oacc[fm][nd] = __builtin_amdgcn_mfma_f32_16x16x32_bf16(af[fm], bv[nd], oacc[fm][nd], 0, 0, 0);
      __builtin_amdgcn_s_setprio(0);
    }
  }

  // ---------------- O reduction across waves in LDS (JF slice dead after loop)
  #pragma unroll
  for (int fm = 0; fm < 2; ++fm)
    #pragma unroll
    for (int nd = 0; nd < 4; ++nd)
      #pragma unroll
      for (int r = 0; r < 4; ++r)
        JFW[(fm * 16 + l4 * 4 + r) * 64 + nd * 16 + l15] = oacc[fm][nd][r];
  __syncthreads();
  {
    int row = tid >> 3;
    int d0 = (tid & 7) * 8;
    const float* j0p = (const float*)Ubuf;
    union { unsigned short u[8]; short8 v; } o;
    #pragma unroll
    for (int e = 0; e < 8; ++e) {
      int idx = row * 64 + d0 + e;
      float s = j0p[idx] + j0p[2048 + idx] + j0p[4096 + idx] + j0p[6144 + idx];
      o.u[e] = __bfloat16_as_ushort(__float2bfloat16(s));
    }
    *(short8*)&ao[(size_t)(i0 + row) * DM + h * HD + d0] = o.v;
  }
}

// ---------------------------------------------------------------- K4: proj GEMM -> d_out (f32)
__global__ __launch_bounds__(256) void k_gemm_proj(const bf16* __restrict__ A,
                                                   const bf16* __restrict__ B,
                                                   const float* __restrict__ bias,
                                                   float* __restrict__ out) {
  __shared__ bf16 As[128 * 64], Bs[128 * 64];
  const int tid = threadIdx.x, lane = tid & 63;
  const int wid = tid >> 6, wm = wid >> 1, wn = wid & 1;
  const int l15 = lane & 15, l4 = lane >> 4;
  const int m0 = blockIdx.x * 128, n0 = blockIdx.y * 128;
  f32x4 acc[4][4] = {};
  gemm_core(A, B, m0, n0, DM, tid, As, Bs, acc);
  #pragma unroll
  for (int im = 0; im < 4; ++im)
    #pragma unroll
    for (int in = 0; in < 4; ++in) {
      int col = n0 + wn * 64 + in * 16 + l15;
      float bval = bias[col];
      #pragma unroll
      for (int r = 0; r < 4; ++r) {
        int row = m0 + wm * 64 + im * 16 + l4 * 4 + r;
        out[(size_t)row * DM + col] = acc[im][in][r] + bval;
      }
    }
}

// ---------------------------------------------------------------- launch
extern "C" void kernel_launch(void* const* d_in, const int* in_sizes, int n_in,
                              void* d_out, int out_size, void* d_ws, size_t ws_size,
                              hipStream_t stream) {
  (void)in_sizes; (void)n_in; (void)out_size; (void)ws_size;
  const float* x  = (const float*)d_in[0];
  const float* wq = (const float*)d_in[1];
  const float* bq = (const float*)d_in[2];
  const float* wp = (const float*)d_in[3];
  const float* bp = (const float*)d_in[4];
  float* out  = (float*)d_out;
  float* attn = out + (size_t)SEQ * DM;

  char* ws = (char*)d_ws;
  bf16* xb    = (bf16*)(ws + (size_t) 0);          // 4 MB  x bf16
  bf16* wqb   = (bf16*)(ws + ((size_t)4  << 20));  // 6 MB  w_qkv bf16
  bf16* wpb   = (bf16*)(ws + ((size_t)10 << 20));  // 2 MB  w_proj bf16
  bf16* qarr  = (bf16*)(ws + ((size_t)12 << 20));  // 4 MB  q [h][i][d] (scale*log2e folded)
  bf16* karr  = (bf16*)(ws + ((size_t)16 << 20));  // 4 MB  k [h][j][d]
  bf16* vt    = (bf16*)(ws + ((size_t)24 << 20));  // 4 MB  vT [h][d][j] (qkv epilogue)
  bf16* ao    = (bf16*)(ws + ((size_t)28 << 20));  // 4 MB  attn-out rows [i][h*64+d]

  k_cvt<<<dim3(1024), dim3(256), 0, stream>>>(x, wq, wp, xb, wqb, wpb);
  k_gemm_qkv<<<dim3(16, 24), dim3(256), 0, stream>>>(xb, wqb, bq, qarr, karr, vt);
  k_attn<<<dim3(1024), dim3(256), 0, stream>>>(qarr, karr, vt, attn, ao);
  k_gemm_proj<<<dim3(16, 8), dim3(256), 0, stream>>>(ao, wpb, bp, out);
}

// Round 11
// 152.106 us; speedup vs baseline: 2.0031x; 2.0031x over previous
//
#include <hip/hip_runtime.h>
#include <hip/hip_bf16.h>

typedef __hip_bfloat16 bf16;
typedef __attribute__((ext_vector_type(8))) short short8;
typedef __attribute__((ext_vector_type(4))) float f32x4;

#define DEV static __device__ __forceinline__

static constexpr int SEQ = 2048;
static constexpr int DM  = 1024;
static constexpr int NH  = 16;
static constexpr int HD  = 64;
static constexpr int WIN = 2048;
static constexpr int PAD = 1024;   // WIN/2

// async global->LDS, 16B per lane; LDS dest = wave-uniform base + lane*16
DEV void async16(const void* g, void* l) {
  __builtin_amdgcn_global_load_lds(
      (__attribute__((address_space(1))) void*)(g),
      (__attribute__((address_space(3))) void*)(l), 16, 0, 0);
}

// ---------------------------------------------------------------- K0: f32 -> bf16 convert (x, w_qkv, w_proj)
__global__ __launch_bounds__(256) void k_cvt(const float* __restrict__ x,
                                             const float* __restrict__ wq,
                                             const float* __restrict__ wp,
                                             bf16* __restrict__ xb,
                                             bf16* __restrict__ wqb,
                                             bf16* __restrict__ wpb) {
  const int NX = SEQ * DM, NQ = 3 * DM * DM, NP = DM * DM;
  const int tot = (NX + NQ + NP) >> 2;
  const int stride = gridDim.x * 256;
  for (int i = blockIdx.x * 256 + threadIdx.x; i < tot; i += stride) {
    int e = i << 2;
    const float* s; bf16* d; int o;
    if (e < NX)            { s = x;  d = xb;  o = e; }
    else if (e < NX + NQ)  { s = wq; d = wqb; o = e - NX; }
    else                   { s = wp; d = wpb; o = e - NX - NQ; }
    float4 v = *(const float4*)(s + o);
    __align__(8) bf16 t4[4] = {__float2bfloat16(v.x), __float2bfloat16(v.y),
                               __float2bfloat16(v.z), __float2bfloat16(v.w)};
    *(uint2*)(d + o) = *(uint2*)t4;
  }
}

// ---------------------------------------------------------------- shared GEMM core: C[m][n] = sum_k A[m][k]*B[n][k]
DEV void gemm_core(const bf16* __restrict__ A, const bf16* __restrict__ B,
                   int m0, int n0, int K, int tid, bf16* As, bf16* Bs,
                   f32x4 (&acc)[4][4]) {
  const int lane = tid & 63, wid = tid >> 6;
  const int wm = wid >> 1, wn = wid & 1;
  const int l15 = lane & 15, l4 = lane >> 4;
  for (int k0 = 0; k0 < K; k0 += 64) {
    __syncthreads();
    #pragma unroll
    for (int it = 0; it < 4; ++it) {
      int rb = it * 32 + wid * 8;
      int r  = rb + (lane >> 3);
      int c  = (lane & 7) * 8;
      async16(A + (size_t)(m0 + r) * K + k0 + c, As + rb * 64);
      async16(B + (size_t)(n0 + r) * K + k0 + c, Bs + rb * 64);
    }
    asm volatile("s_waitcnt vmcnt(0)" ::: "memory");
    __syncthreads();
    #pragma unroll
    for (int kk = 0; kk < 2; ++kk) {
      short8 a[4], b[4];
      #pragma unroll
      for (int im = 0; im < 4; ++im)
        a[im] = *(const short8*)(As + (wm * 64 + im * 16 + l15) * 64 + kk * 32 + l4 * 8);
      #pragma unroll
      for (int in = 0; in < 4; ++in)
        b[in] = *(const short8*)(Bs + (wn * 64 + in * 16 + l15) * 64 + kk * 32 + l4 * 8);
      #pragma unroll
      for (int im = 0; im < 4; ++im)
        #pragma unroll
        for (int in = 0; in < 4; ++in)
          acc[im][in] = __builtin_amdgcn_mfma_f32_16x16x32_bf16(a[im], b[in], acc[im][in], 0, 0, 0);
    }
  }
}

// ---------------------------------------------------------------- K1: qkv GEMM + scatter to q(scaled)/k/vT
__global__ __launch_bounds__(256) void k_gemm_qkv(const bf16* __restrict__ A,
                                                  const bf16* __restrict__ B,
                                                  const float* __restrict__ bias,
                                                  bf16* __restrict__ qo,
                                                  bf16* __restrict__ ko,
                                                  bf16* __restrict__ vt) {
  __shared__ bf16 As[128 * 64], Bs[128 * 64];
  const int tid = threadIdx.x, lane = tid & 63;
  const int wid = tid >> 6, wm = wid >> 1, wn = wid & 1;
  const int l15 = lane & 15, l4 = lane >> 4;
  const int m0 = blockIdx.x * 128, n0 = blockIdx.y * 128;
  f32x4 acc[4][4] = {};
  gemm_core(A, B, m0, n0, DM, tid, As, Bs, acc);
  #pragma unroll
  for (int im = 0; im < 4; ++im)
    #pragma unroll
    for (int in = 0; in < 4; ++in) {
      int col = n0 + wn * 64 + in * 16 + l15;
      float bval = bias[col];
      int t = col >> 10, h = (col >> 6) & 15, dd = col & 63;
      int row0 = m0 + wm * 64 + im * 16 + l4 * 4;
      if (t == 2) {
        // v transposed directly: vT[h][dd][j], 4 consecutive j -> one 8B store
        __align__(8) bf16 t4[4];
        #pragma unroll
        for (int r = 0; r < 4; ++r)
          t4[r] = __float2bfloat16(acc[im][in][r] + bval);
        *(uint2*)&vt[((size_t)h * HD + dd) * SEQ + row0] = *(uint2*)t4;
      } else {
        #pragma unroll
        for (int r = 0; r < 4; ++r) {
          float v = acc[im][in][r] + bval;
          size_t idx = ((size_t)h * SEQ + row0 + r) * HD + dd;
          // q folded with hd^-0.5 * log2(e) so scores feed exp2 directly
          if (t == 0) qo[idx] = __float2bfloat16(v * 0.18033688011112042f);
          else        ko[idx] = __float2bfloat16(v);
        }
      }
    }
}

// ---------------------------------------------------------------- attn helpers
DEV void stage_kp(const bf16* kbase, int i0, int tt, int lane, bf16* dst) {
  #pragma unroll
  for (int it = 0; it < 4; ++it) {
    int r  = it * 8 + (lane >> 3);
    int cg = lane & 7;
    int jp = i0 + tt * 32 + r;                 // absolute j'
    int krow = jp - PAD;                       // clamp; pad handled analytically
    krow = krow < 0 ? 0 : (krow > SEQ - 1 ? SEQ - 1 : krow);
    int sc = (cg ^ (r & 7)) * 8;               // pre-swizzled global source
    async16(kbase + (size_t)krow * HD + sc, dst + it * 8 * 64);
  }
}

// LDS K -> MFMA, unswapped: sf[fm][fn]: col=j'(l15), row=i(l4*4+r)
DEV void qk_mfma_lds(const bf16* KPb, const short8 (&qf)[2][2], int l15, int l4,
                     f32x4 (&sf)[2][2]) {
  __builtin_amdgcn_s_setprio(1);
  #pragma unroll
  for (int kg = 0; kg < 2; ++kg) {
    short8 kfr[2];
    #pragma unroll
    for (int fn = 0; fn < 2; ++fn) {
      int jl = fn * 16 + l15;
      int pg = (kg * 4 + l4) ^ (jl & 7);
      kfr[fn] = *(const short8*)&KPb[jl * 64 + pg * 8];
    }
    #pragma unroll
    for (int fm = 0; fm < 2; ++fm)
      #pragma unroll
      for (int fn = 0; fn < 2; ++fn)
        sf[fm][fn] = __builtin_amdgcn_mfma_f32_16x16x32_bf16(qf[fm][kg], kfr[fn], sf[fm][fn], 0, 0, 0);
  }
  __builtin_amdgcn_s_setprio(0);
}

// swapped variant for attn1 (LDS K): sf[fj][fi]: col=i(l15), row=j'(l4*4+r)
DEV void qk_mfma_lds_sw(const bf16* KPb, const short8 (&qf)[2][2], int l15, int l4,
                        f32x4 (&sf)[2][2]) {
  __builtin_amdgcn_s_setprio(1);
  #pragma unroll
  for (int kg = 0; kg < 2; ++kg) {
    short8 kfr[2];
    #pragma unroll
    for (int fj = 0; fj < 2; ++fj) {
      int jl = fj * 16 + l15;
      int pg = (kg * 4 + l4) ^ (jl & 7);
      kfr[fj] = *(const short8*)&KPb[jl * 64 + pg * 8];
    }
    #pragma unroll
    for (int fj = 0; fj < 2; ++fj)
      #pragma unroll
      for (int fi = 0; fi < 2; ++fi)
        sf[fj][fi] = __builtin_amdgcn_mfma_f32_16x16x32_bf16(kfr[fj], qf[fi][kg], sf[fj][fi], 0, 0, 0);
  }
  __builtin_amdgcn_s_setprio(0);
}

DEV int pad_lo(int i0) { int d = PAD - i0; return d <= 0 ? 0 : (d >> 5); }
DEV int pad_hi(int i0) { int t = ((PAD + SEQ - 1 - i0) >> 5) + 1; return t > 65 ? 65 : t; }

// ---------------------------------------------------------------- K2a: partial exp-sums, 4 chunk-waves per 256-thread block
__global__ __launch_bounds__(256) void k_attn1(const bf16* __restrict__ q,
                                               const bf16* __restrict__ kkk,
                                               float* __restrict__ psums) {
  const int h  = blockIdx.x >> 6;
  const int i0 = (blockIdx.x & 63) << 5;
  const int tid = threadIdx.x;
  const int c = tid >> 6;                     // wave = chunk
  const int lane = tid & 63;
  const int l15 = lane & 15, l4 = lane >> 4;

  __shared__ bf16 KP[4][2][32 * 64];          // per-wave double buffer (32 KB)

  constexpr int st[5] = {0, 16, 32, 48, 65};
  const int lo_g = pad_lo(i0), hi_g = pad_hi(i0);
  int lo = st[c] > lo_g ? st[c] : lo_g;
  int hi = st[c + 1] < hi_g ? st[c + 1] : hi_g;

  short8 qf[2][2];
  #pragma unroll
  for (int fi = 0; fi < 2; ++fi)
    #pragma unroll
    for (int kg = 0; kg < 2; ++kg)
      qf[fi][kg] = *(const short8*)&q[((size_t)h * SEQ + i0 + fi * 16 + l15) * HD + kg * 32 + l4 * 8];

  const bf16* kbase = kkk + (size_t)h * SEQ * HD;

  float psum[2] = {0.f, 0.f};
  if (lo < hi) {
    stage_kp(kbase, i0, lo, lane, KP[c][lo & 1]);
    for (int tt = lo; tt < hi; ++tt) {
      int nxt = (tt + 1 < hi) ? tt + 1 : tt;
      stage_kp(kbase, i0, nxt, lane, KP[c][(tt + 1) & 1]);
      asm volatile("s_waitcnt vmcnt(4)" ::: "memory");
      f32x4 sf[2][2] = {};
      qk_mfma_lds_sw(KP[c][tt & 1], qf, l15, l4, sf);
      const bool interior = (tt >= 1) && (tt <= 63) &&
                            (i0 + tt * 32 >= PAD) && (i0 + tt * 32 + 31 < PAD + SEQ);
      if (interior) {
        #pragma unroll
        for (int fj = 0; fj < 2; ++fj)
          #pragma unroll
          for (int r = 0; r < 4; ++r) {
            psum[0] += __builtin_amdgcn_exp2f(sf[fj][0][r]);
            psum[1] += __builtin_amdgcn_exp2f(sf[fj][1][r]);
          }
      } else {
        #pragma unroll
        for (int fj = 0; fj < 2; ++fj)
          #pragma unroll
          for (int r = 0; r < 4; ++r) {
            int jj = tt * 32 + fj * 16 + l4 * 4 + r;   // local j'
            int jp = i0 + jj;                          // absolute j'
            bool pad = (jp < PAD) || (jp >= PAD + SEQ);
            #pragma unroll
            for (int fi = 0; fi < 2; ++fi) {
              int iloc = fi * 16 + l15;
              float e = pad ? 1.0f : __builtin_amdgcn_exp2f(sf[fj][fi][r]);
              if ((unsigned)(jj - iloc) < (unsigned)WIN) psum[fi] += e;
            }
          }
      }
    }
  }
  float r0 = psum[0];
  r0 += __shfl_xor(r0, 16); r0 += __shfl_xor(r0, 32);
  float r1 = psum[1];
  r1 += __shfl_xor(r1, 16); r1 += __shfl_xor(r1, 32);
  if (lane < 32) {
    int i_abs = i0 + lane;
    float s = (lane < 16) ? r0 : r1;
    if (c == 0) {
      int cl = i0 + lo_g * 32 - i_abs; if (cl < 0) cl = 0;
      int cr = i_abs + WIN - (i0 + hi_g * 32); if (cr < 0) cr = 0;
      s += (float)(cl + cr);                  // analytic all-pad contribution
    }
    psums[((size_t)c * NH + h) * SEQ + i_abs] = s;
  }
}

// ---------------------------------------------------------------- K2b: recompute + normalize + aligned flush + PV
// 4 chunk-waves per 256-thread block; per-wave private KP/JF; barriers only at the
// end for the in-block O reduction (replaces aof atomics + k_ored).
__global__ __launch_bounds__(256) void k_attn2(const bf16* __restrict__ q,
                                               const bf16* __restrict__ kkk,
                                               const bf16* __restrict__ vT,
                                               const float* __restrict__ psums,
                                               float* __restrict__ attn,
                                               bf16* __restrict__ ao) {
  const int h  = blockIdx.x >> 6;
  const int i0 = (blockIdx.x & 63) << 5;
  const int tid = threadIdx.x;
  const int c = tid >> 6;                     // wave = chunk
  const int lane = tid & 63;
  const int l15 = lane & 15, l4 = lane >> 4;
  const int c0 = c * 16, c1 = c0 + 16;
  const int lo_g = pad_lo(i0), hi_g = pad_hi(i0);

  __shared__ bf16 KP[4][2][32 * 64];          // 32 KB
  __shared__ float JF[4][32 * 64];            // 32 KB, per-wave j-aligned f32 ring

  float inv[2][4];
  #pragma unroll
  for (int fm = 0; fm < 2; ++fm)
    #pragma unroll
    for (int r = 0; r < 4; ++r) {
      int row = i0 + fm * 16 + l4 * 4 + r;
      float s = 0.f;
      #pragma unroll
      for (int cc = 0; cc < 4; ++cc)
        s += psums[((size_t)cc * NH + h) * SEQ + row];
      inv[fm][r] = __builtin_amdgcn_rcpf(s);
    }

  short8 qf[2][2];
  #pragma unroll
  for (int fm = 0; fm < 2; ++fm)
    #pragma unroll
    for (int kg = 0; kg < 2; ++kg)
      qf[fm][kg] = *(const short8*)&q[((size_t)h * SEQ + i0 + fm * 16 + l15) * HD + kg * 32 + l4 * 8];

  const bf16* kbase = kkk + (size_t)h * SEQ * HD;
  const bf16* vbase = vT + (size_t)h * HD * SEQ;
  float* abase = attn + (size_t)(h * SEQ + i0) * WIN;
  float* JFW = JF[c];

  f32x4 oacc[2][4] = {};
  stage_kp(kbase, i0, c0, lane, KP[c][0]);     // c0 even -> buf 0
  for (int tt = c0; tt <= c1; ++tt) {
    short8 bv[4];
    if (tt > c0) {
      int jb = (tt - 1) * 32;
      #pragma unroll
      for (int nd = 0; nd < 4; ++nd)
        bv[nd] = *(const short8*)&vbase[(size_t)(nd * 16 + l15) * SEQ + jb + l4 * 8];
    }
    int nxt = (tt < c1) ? tt + 1 : tt;
    stage_kp(kbase, i0, nxt, lane, KP[c][(tt + 1) & 1]);
    // counted wait for stage(tt): younger = stores(t-1)[4]+bv[4]+stage(t+1)[4]
    if (tt == c0)          asm volatile("s_waitcnt vmcnt(4)" ::: "memory");
    else if (tt == c0 + 1) asm volatile("s_waitcnt vmcnt(8)" ::: "memory");
    else                   asm volatile("s_waitcnt vmcnt(12)" ::: "memory");

    const bool fp = (tt < lo_g) || (tt >= hi_g);   // all-pad tile: score==0
    f32x4 sf[2][2] = {};
    if (!fp) qk_mfma_lds(KP[c][tt & 1], qf, l15, l4, sf);

    // re-bin diagonal tile into j-aligned JF ring
    const bool allv = (i0 + tt * 32 >= PAD) && (i0 + tt * 32 + 31 < PAD + SEQ);
    #pragma unroll
    for (int fm = 0; fm < 2; ++fm)
      #pragma unroll
      for (int fn = 0; fn < 2; ++fn) {
        int J0 = tt * 32 + fn * 16 + l15;          // local j' (col)
        bool padc = fp || (!allv && ((i0 + J0 < PAD) || (i0 + J0 >= PAD + SEQ)));
        #pragma unroll
        for (int r = 0; r < 4; ++r) {
          int row = fm * 16 + l4 * 4 + r;          // local i
          float e = padc ? 1.0f : __builtin_amdgcn_exp2f(sf[fm][fn][r]);
          float val = e * inv[fm][r];
          int j6 = (J0 - row) & 63;                // ring position
          int pgrp = (j6 >> 2) ^ ((row & 7) << 1);
          JFW[row * 64 + pgrp * 4 + (j6 & 3)] = val;
        }
      }

    if (tt > c0) {
      const int g = (tt - 1) & 1;                  // ring slot of completed j-tile
      const int Jb = (tt - 1) * 32;
      #pragma unroll
      for (int s = 0; s < 4; ++s) {
        int row = s * 8 + (lane >> 3);
        int c8 = lane & 7;
        int pgrp = (g * 8 + c8) ^ ((row & 7) << 1);
        f32x4 vv = *(const f32x4*)&JFW[row * 64 + pgrp * 4];
        __builtin_nontemporal_store(vv, (f32x4*)(abase + (size_t)row * WIN + Jb + c8 * 4));
      }
      short8 af[2];
      #pragma unroll
      for (int fm = 0; fm < 2; ++fm) {
        int row = fm * 16 + l15;
        int pg0 = (g * 8 + l4 * 2) ^ ((row & 7) << 1);
        const float* p = &JFW[row * 64 + pg0 * 4];
        union { unsigned short u[8]; short8 v; } tmp;
        #pragma unroll
        for (int e = 0; e < 8; ++e)
          tmp.u[e] = __bfloat16_as_ushort(__float2bfloat16(p[e]));
        af[fm] = tmp.v;
      }
      __builtin_amdgcn_s_setprio(1);
      #pragma unroll
      for (int fm = 0; fm < 2; ++fm)
        #pragma unroll
        for (int nd = 0; nd < 4; ++nd)
          oacc[fm][nd] = __builtin_amdgcn_mfma_f32_16x16x32_bf16(af[fm], bv[nd], oacc[fm][nd], 0, 0, 0);
      __builtin_amdgcn_s_setprio(0);
    }
  }

  // ---------------- in-block O reduction (JF slices dead after PV loop)
  #pragma unroll
  for (int fm = 0; fm < 2; ++fm)
    #pragma unroll
    for (int nd = 0; nd < 4; ++nd)
      #pragma unroll
      for (int r = 0; r < 4; ++r)
        JFW[(fm * 16 + l4 * 4 + r) * 64 + nd * 16 + l15] = oacc[fm][nd][r];
  __syncthreads();
  {
    int row = tid >> 3;
    int d0 = (tid & 7) * 8;
    const float* j0p = &JF[0][0];
    union { unsigned short u[8]; short8 v; } o;
    #pragma unroll
    for (int e = 0; e < 8; ++e) {
      int idx = row * 64 + d0 + e;
      float s = j0p[idx] + j0p[2048 + idx] + j0p[4096 + idx] + j0p[6144 + idx];
      o.u[e] = __bfloat16_as_ushort(__float2bfloat16(s));
    }
    *(short8*)&ao[(size_t)(i0 + row) * DM + h * HD + d0] = o.v;
  }
}

// ---------------------------------------------------------------- K4: proj GEMM -> d_out (f32)
__global__ __launch_bounds__(256) void k_gemm_proj(const bf16* __restrict__ A,
                                                   const bf16* __restrict__ B,
                                                   const float* __restrict__ bias,
                                                   float* __restrict__ out) {
  __shared__ bf16 As[128 * 64], Bs[128 * 64];
  const int tid = threadIdx.x, lane = tid & 63;
  const int wid = tid >> 6, wm = wid >> 1, wn = wid & 1;
  const int l15 = lane & 15, l4 = lane >> 4;
  const int m0 = blockIdx.x * 128, n0 = blockIdx.y * 128;
  f32x4 acc[4][4] = {};
  gemm_core(A, B, m0, n0, DM, tid, As, Bs, acc);
  #pragma unroll
  for (int im = 0; im < 4; ++im)
    #pragma unroll
    for (int in = 0; in < 4; ++in) {
      int col = n0 + wn * 64 + in * 16 + l15;
      float bval = bias[col];
      #pragma unroll
      for (int r = 0; r < 4; ++r) {
        int row = m0 + wm * 64 + im * 16 + l4 * 4 + r;
        out[(size_t)row * DM + col] = acc[im][in][r] + bval;
      }
    }
}

// ---------------------------------------------------------------- launch
extern "C" void kernel_launch(void* const* d_in, const int* in_sizes, int n_in,
                              void* d_out, int out_size, void* d_ws, size_t ws_size,
                              hipStream_t stream) {
  (void)in_sizes; (void)n_in; (void)out_size; (void)ws_size;
  const float* x  = (const float*)d_in[0];
  const float* wq = (const float*)d_in[1];
  const float* bq = (const float*)d_in[2];
  const float* wp = (const float*)d_in[3];
  const float* bp = (const float*)d_in[4];
  float* out  = (float*)d_out;
  float* attn = out + (size_t)SEQ * DM;

  char* ws = (char*)d_ws;
  bf16* xb    = (bf16*)(ws + (size_t) 0);          // 4 MB  x bf16
  bf16* wqb   = (bf16*)(ws + ((size_t)4  << 20));  // 6 MB  w_qkv bf16
  bf16* wpb   = (bf16*)(ws + ((size_t)10 << 20));  // 2 MB  w_proj bf16
  bf16* qarr  = (bf16*)(ws + ((size_t)12 << 20));  // 4 MB  q [h][i][d] (scale*log2e folded)
  bf16* karr  = (bf16*)(ws + ((size_t)16 << 20));  // 4 MB  k [h][j][d]
  bf16* vt    = (bf16*)(ws + ((size_t)24 << 20));  // 4 MB  vT [h][d][j] (qkv epilogue)
  bf16* ao    = (bf16*)(ws + ((size_t)28 << 20));  // 4 MB  attn-out rows [i][h*64+d]
  float* psums= (float*)(ws + ((size_t)8 << 20));  // 512KB partial sums (overlays wqb tail, dead by then)

  k_cvt<<<dim3(1024), dim3(256), 0, stream>>>(x, wq, wp, xb, wqb, wpb);
  k_gemm_qkv<<<dim3(16, 24), dim3(256), 0, stream>>>(xb, wqb, bq, qarr, karr, vt);
  k_attn1<<<dim3(1024), dim3(256), 0, stream>>>(qarr, karr, psums);
  k_attn2<<<dim3(1024), dim3(256), 0, stream>>>(qarr, karr, vt, psums, attn, ao);
  k_gemm_proj<<<dim3(16, 8), dim3(256), 0, stream>>>(ao, wpb, bp, out);
}

// Round 12
// 150.477 us; speedup vs baseline: 2.0248x; 1.0108x over previous
//
#include <hip/hip_runtime.h>
#include <hip/hip_bf16.h>

typedef __hip_bfloat16 bf16;
typedef __attribute__((ext_vector_type(8))) short short8;
typedef __attribute__((ext_vector_type(4))) float f32x4;
typedef __attribute__((ext_vector_type(4))) unsigned short ushort4v;

#define DEV static __device__ __forceinline__

static constexpr int SEQ = 2048;
static constexpr int DM  = 1024;
static constexpr int NH  = 16;
static constexpr int HD  = 64;
static constexpr int WIN = 2048;
static constexpr int PAD = 1024;   // WIN/2

// async global->LDS, 16B per lane; LDS dest = wave-uniform base + lane*16
DEV void async16(const void* g, void* l) {
  __builtin_amdgcn_global_load_lds(
      (__attribute__((address_space(1))) void*)(g),
      (__attribute__((address_space(3))) void*)(l), 16, 0, 0);
}

// ---------------------------------------------------------------- K0: f32 -> bf16 convert (x, w_qkv, w_proj)
__global__ __launch_bounds__(256) void k_cvt(const float* __restrict__ x,
                                             const float* __restrict__ wq,
                                             const float* __restrict__ wp,
                                             bf16* __restrict__ xb,
                                             bf16* __restrict__ wqb,
                                             bf16* __restrict__ wpb) {
  const int NX = SEQ * DM, NQ = 3 * DM * DM, NP = DM * DM;
  const int tot = (NX + NQ + NP) >> 2;
  const int stride = gridDim.x * 256;
  for (int i = blockIdx.x * 256 + threadIdx.x; i < tot; i += stride) {
    int e = i << 2;
    const float* s; bf16* d; int o;
    if (e < NX)            { s = x;  d = xb;  o = e; }
    else if (e < NX + NQ)  { s = wq; d = wqb; o = e - NX; }
    else                   { s = wp; d = wpb; o = e - NX - NQ; }
    float4 v = *(const float4*)(s + o);
    __align__(8) bf16 t4[4] = {__float2bfloat16(v.x), __float2bfloat16(v.y),
                               __float2bfloat16(v.z), __float2bfloat16(v.w)};
    *(uint2*)(d + o) = *(uint2*)t4;
  }
}

// ---------------------------------------------------------------- shared GEMM core: C[m][n] = sum_k A[m][k]*B[n][k]
DEV void gemm_core(const bf16* __restrict__ A, const bf16* __restrict__ B,
                   int m0, int n0, int K, int tid, bf16* As, bf16* Bs,
                   f32x4 (&acc)[4][4]) {
  const int lane = tid & 63, wid = tid >> 6;
  const int wm = wid >> 1, wn = wid & 1;
  const int l15 = lane & 15, l4 = lane >> 4;
  for (int k0 = 0; k0 < K; k0 += 64) {
    __syncthreads();
    #pragma unroll
    for (int it = 0; it < 4; ++it) {
      int rb = it * 32 + wid * 8;
      int r  = rb + (lane >> 3);
      int c  = (lane & 7) * 8;
      async16(A + (size_t)(m0 + r) * K + k0 + c, As + rb * 64);
      async16(B + (size_t)(n0 + r) * K + k0 + c, Bs + rb * 64);
    }
    asm volatile("s_waitcnt vmcnt(0)" ::: "memory");
    __syncthreads();
    #pragma unroll
    for (int kk = 0; kk < 2; ++kk) {
      short8 a[4], b[4];
      #pragma unroll
      for (int im = 0; im < 4; ++im)
        a[im] = *(const short8*)(As + (wm * 64 + im * 16 + l15) * 64 + kk * 32 + l4 * 8);
      #pragma unroll
      for (int in = 0; in < 4; ++in)
        b[in] = *(const short8*)(Bs + (wn * 64 + in * 16 + l15) * 64 + kk * 32 + l4 * 8);
      #pragma unroll
      for (int im = 0; im < 4; ++im)
        #pragma unroll
        for (int in = 0; in < 4; ++in)
          acc[im][in] = __builtin_amdgcn_mfma_f32_16x16x32_bf16(a[im], b[in], acc[im][in], 0, 0, 0);
    }
  }
}

// ---------------------------------------------------------------- K1: qkv GEMM + scatter to q(scaled)/k/vT
__global__ __launch_bounds__(256) void k_gemm_qkv(const bf16* __restrict__ A,
                                                  const bf16* __restrict__ B,
                                                  const float* __restrict__ bias,
                                                  bf16* __restrict__ qo,
                                                  bf16* __restrict__ ko,
                                                  bf16* __restrict__ vt) {
  __shared__ bf16 As[128 * 64], Bs[128 * 64];
  const int tid = threadIdx.x, lane = tid & 63;
  const int wid = tid >> 6, wm = wid >> 1, wn = wid & 1;
  const int l15 = lane & 15, l4 = lane >> 4;
  const int m0 = blockIdx.x * 128, n0 = blockIdx.y * 128;
  f32x4 acc[4][4] = {};
  gemm_core(A, B, m0, n0, DM, tid, As, Bs, acc);
  #pragma unroll
  for (int im = 0; im < 4; ++im)
    #pragma unroll
    for (int in = 0; in < 4; ++in) {
      int col = n0 + wn * 64 + in * 16 + l15;
      float bval = bias[col];
      int t = col >> 10, h = (col >> 6) & 15, dd = col & 63;
      int row0 = m0 + wm * 64 + im * 16 + l4 * 4;
      if (t == 2) {
        // v transposed directly: vT[h][dd][j], 4 consecutive j -> one 8B store
        __align__(8) bf16 t4[4];
        #pragma unroll
        for (int r = 0; r < 4; ++r)
          t4[r] = __float2bfloat16(acc[im][in][r] + bval);
        *(uint2*)&vt[((size_t)h * HD + dd) * SEQ + row0] = *(uint2*)t4;
      } else {
        #pragma unroll
        for (int r = 0; r < 4; ++r) {
          float v = acc[im][in][r] + bval;
          size_t idx = ((size_t)h * SEQ + row0 + r) * HD + dd;
          // q folded with hd^-0.5 * log2(e) so scores feed exp2 directly
          if (t == 0) qo[idx] = __float2bfloat16(v * 0.18033688011112042f);
          else        ko[idx] = __float2bfloat16(v);
        }
      }
    }
}

// ---------------------------------------------------------------- attn helpers
DEV void stage_kp(const bf16* kbase, int i0, int tt, int lane, bf16* dst) {
  #pragma unroll
  for (int it = 0; it < 4; ++it) {
    int r  = it * 8 + (lane >> 3);
    int cg = lane & 7;
    int jp = i0 + tt * 32 + r;                 // absolute j'
    int krow = jp - PAD;                       // clamp; pad handled analytically
    krow = krow < 0 ? 0 : (krow > SEQ - 1 ? SEQ - 1 : krow);
    int sc = (cg ^ (r & 7)) * 8;               // pre-swizzled global source
    async16(kbase + (size_t)krow * HD + sc, dst + it * 8 * 64);
  }
}

// LDS K -> MFMA, unswapped: sf[fm][fn]: col=j'(l15), row=i(l4*4+r)
DEV void qk_mfma_lds(const bf16* KPb, const short8 (&qf)[2][2], int l15, int l4,
                     f32x4 (&sf)[2][2]) {
  __builtin_amdgcn_s_setprio(1);
  #pragma unroll
  for (int kg = 0; kg < 2; ++kg) {
    short8 kfr[2];
    #pragma unroll
    for (int fn = 0; fn < 2; ++fn) {
      int jl = fn * 16 + l15;
      int pg = (kg * 4 + l4) ^ (jl & 7);
      kfr[fn] = *(const short8*)&KPb[jl * 64 + pg * 8];
    }
    #pragma unroll
    for (int fm = 0; fm < 2; ++fm)
      #pragma unroll
      for (int fn = 0; fn < 2; ++fn)
        sf[fm][fn] = __builtin_amdgcn_mfma_f32_16x16x32_bf16(qf[fm][kg], kfr[fn], sf[fm][fn], 0, 0, 0);
  }
  __builtin_amdgcn_s_setprio(0);
}

// swapped variant (phase 1): sf[fj][fi]: col=i(l15), row=j'(l4*4+r)
DEV void qk_mfma_lds_sw(const bf16* KPb, const short8 (&qf)[2][2], int l15, int l4,
                        f32x4 (&sf)[2][2]) {
  __builtin_amdgcn_s_setprio(1);
  #pragma unroll
  for (int kg = 0; kg < 2; ++kg) {
    short8 kfr[2];
    #pragma unroll
    for (int fj = 0; fj < 2; ++fj) {
      int jl = fj * 16 + l15;
      int pg = (kg * 4 + l4) ^ (jl & 7);
      kfr[fj] = *(const short8*)&KPb[jl * 64 + pg * 8];
    }
    #pragma unroll
    for (int fj = 0; fj < 2; ++fj)
      #pragma unroll
      for (int fi = 0; fi < 2; ++fi)
        sf[fj][fi] = __builtin_amdgcn_mfma_f32_16x16x32_bf16(kfr[fj], qf[fi][kg], sf[fj][fi], 0, 0, 0);
  }
  __builtin_amdgcn_s_setprio(0);
}

DEV int pad_lo(int i0) { int d = PAD - i0; return d <= 0 ? 0 : (d >> 5); }
DEV int pad_hi(int i0) { int t = ((PAD + SEQ - 1 - i0) >> 5) + 1; return t > 65 ? 65 : t; }

// ---------------------------------------------------------------- K2: merged attn (sum pass + normalize/flush/PV pass)
// block = (h, i0); 4 chunk-waves. LDS: KP 32KB (reused as f32 O-exchange) +
// JFB 16KB raw-e bf16 ring -> ~50KB -> 3 blocks/CU.
__global__ __launch_bounds__(256) void k_attn(const bf16* __restrict__ q,
                                              const bf16* __restrict__ kkk,
                                              const bf16* __restrict__ vT,
                                              float* __restrict__ attn,
                                              bf16* __restrict__ ao) {
  const int h  = blockIdx.x >> 6;
  const int i0 = (blockIdx.x & 63) << 5;
  const int tid = threadIdx.x;
  const int c = tid >> 6;                     // wave = chunk
  const int lane = tid & 63;
  const int l15 = lane & 15, l4 = lane >> 4;
  const int lo_g = pad_lo(i0), hi_g = pad_hi(i0);

  __shared__ bf16 KP[4][2][32 * 64];          // 32 KB; f32 O-exchange after PV
  __shared__ unsigned short JFB[4][32 * 64];  // 16 KB raw-e bf16 ring, 16B-group XOR swizzle
  __shared__ float sums[4][32];
  __shared__ float invL[32];

  short8 qf[2][2];
  #pragma unroll
  for (int fm = 0; fm < 2; ++fm)
    #pragma unroll
    for (int kg = 0; kg < 2; ++kg)
      qf[fm][kg] = *(const short8*)&q[((size_t)h * SEQ + i0 + fm * 16 + l15) * HD + kg * 32 + l4 * 8];

  const bf16* kbase = kkk + (size_t)h * SEQ * HD;
  const bf16* vbase = vT + (size_t)h * HD * SEQ;
  float* abase = attn + (size_t)(h * SEQ + i0) * WIN;

  // ---------------- phase 1: partial exp-sums (swapped QK)
  {
    constexpr int st[5] = {0, 16, 32, 48, 65};
    int lo = st[c] > lo_g ? st[c] : lo_g;
    int hi = st[c + 1] < hi_g ? st[c + 1] : hi_g;

    float psum[2] = {0.f, 0.f};
    if (lo < hi) {
      stage_kp(kbase, i0, lo, lane, KP[c][lo & 1]);
      for (int tt = lo; tt < hi; ++tt) {
        int nxt = (tt + 1 < hi) ? tt + 1 : tt;
        stage_kp(kbase, i0, nxt, lane, KP[c][(tt + 1) & 1]);
        asm volatile("s_waitcnt vmcnt(4)" ::: "memory");
        f32x4 sf[2][2] = {};
        qk_mfma_lds_sw(KP[c][tt & 1], qf, l15, l4, sf);
        const bool interior = (tt >= 1) && (tt <= 63) &&
                              (i0 + tt * 32 >= PAD) && (i0 + tt * 32 + 31 < PAD + SEQ);
        if (interior) {
          #pragma unroll
          for (int fj = 0; fj < 2; ++fj)
            #pragma unroll
            for (int r = 0; r < 4; ++r) {
              psum[0] += __builtin_amdgcn_exp2f(sf[fj][0][r]);
              psum[1] += __builtin_amdgcn_exp2f(sf[fj][1][r]);
            }
        } else {
          #pragma unroll
          for (int fj = 0; fj < 2; ++fj)
            #pragma unroll
            for (int r = 0; r < 4; ++r) {
              int jj = tt * 32 + fj * 16 + l4 * 4 + r;   // local j'
              int jp = i0 + jj;                          // absolute j'
              bool pad = (jp < PAD) || (jp >= PAD + SEQ);
              #pragma unroll
              for (int fi = 0; fi < 2; ++fi) {
                int iloc = fi * 16 + l15;
                float e = pad ? 1.0f : __builtin_amdgcn_exp2f(sf[fj][fi][r]);
                if ((unsigned)(jj - iloc) < (unsigned)WIN) psum[fi] += e;
              }
            }
        }
      }
    }
    float r0 = psum[0];
    r0 += __shfl_xor(r0, 16); r0 += __shfl_xor(r0, 32);
    float r1 = psum[1];
    r1 += __shfl_xor(r1, 16); r1 += __shfl_xor(r1, 32);
    if (lane < 32) {
      int i_abs = i0 + lane;
      float s = (lane < 16) ? r0 : r1;
      if (c == 0) {
        int cl = i0 + lo_g * 32 - i_abs; if (cl < 0) cl = 0;
        int cr = i_abs + WIN - (i0 + hi_g * 32); if (cr < 0) cr = 0;
        s += (float)(cl + cr);                  // analytic all-pad contribution
      }
      sums[c][lane] = s;
    }
  }
  __syncthreads();
  if (tid < 32)
    invL[tid] = __builtin_amdgcn_rcpf(sums[0][tid] + sums[1][tid] +
                                      sums[2][tid] + sums[3][tid]);
  __syncthreads();

  // per-lane flush inverses (row = s2*8 + (lane>>3))
  float invf[4];
  #pragma unroll
  for (int s2 = 0; s2 < 4; ++s2) invf[s2] = invL[s2 * 8 + (lane >> 3)];

  // ---------------- phase 2: recompute QK, raw-e rebin, normalized flush, PV
  const int c0 = c * 16, c1 = c0 + 16;
  unsigned short* JW = JFB[c];
  f32x4 oacc[2][4] = {};
  stage_kp(kbase, i0, c0, lane, KP[c][0]);     // c0 even -> buf 0
  for (int tt = c0; tt <= c1; ++tt) {
    short8 bv[4];
    if (tt > c0) {
      int jb = (tt - 1) * 32;
      #pragma unroll
      for (int nd = 0; nd < 4; ++nd)
        bv[nd] = *(const short8*)&vbase[(size_t)(nd * 16 + l15) * SEQ + jb + l4 * 8];
    }
    int nxt = (tt < c1) ? tt + 1 : tt;
    stage_kp(kbase, i0, nxt, lane, KP[c][(tt + 1) & 1]);
    // counted wait for stage(tt): younger = stores(t-1)[4]+bv[4]+stage(t+1)[4]
    if (tt == c0)          asm volatile("s_waitcnt vmcnt(4)" ::: "memory");
    else if (tt == c0 + 1) asm volatile("s_waitcnt vmcnt(8)" ::: "memory");
    else                   asm volatile("s_waitcnt vmcnt(12)" ::: "memory");

    const bool fp = (tt < lo_g) || (tt >= hi_g);   // all-pad tile: score==0 -> e=1
    f32x4 sf[2][2] = {};
    if (!fp) qk_mfma_lds(KP[c][tt & 1], qf, l15, l4, sf);

    // re-bin raw e (bf16) into j-aligned ring; 16B-group swizzle sg=(j6>>3)^(row&7)
    const bool allv = (i0 + tt * 32 >= PAD) && (i0 + tt * 32 + 31 < PAD + SEQ);
    #pragma unroll
    for (int fm = 0; fm < 2; ++fm)
      #pragma unroll
      for (int fn = 0; fn < 2; ++fn) {
        int J0 = tt * 32 + fn * 16 + l15;          // local j' (col)
        bool padc = fp || (!allv && ((i0 + J0 < PAD) || (i0 + J0 >= PAD + SEQ)));
        #pragma unroll
        for (int r = 0; r < 4; ++r) {
          int row = fm * 16 + l4 * 4 + r;          // local i
          float e = padc ? 1.0f : __builtin_amdgcn_exp2f(sf[fm][fn][r]);
          int j6 = (J0 - row) & 63;                // ring position
          int sg = (j6 >> 3) ^ (row & 7);
          JW[row * 64 + sg * 8 + (j6 & 7)] = __bfloat16_as_ushort(__float2bfloat16(e));
        }
      }

    if (tt > c0) {
      const int g = (tt - 1) & 1;                  // ring slot of completed j-tile
      const int Jb = (tt - 1) * 32;
      const int c8 = lane & 7;
      // flush: normalize raw e with invL at store time; full-128B-line nt stores
      #pragma unroll
      for (int s2 = 0; s2 < 4; ++s2) {
        int row = s2 * 8 + (lane >> 3);
        int sg = (g * 4 + (c8 >> 1)) ^ (row & 7);
        ushort4v uv = *(const ushort4v*)&JW[row * 64 + sg * 8 + (c8 & 1) * 4];
        f32x4 vv;
        #pragma unroll
        for (int e = 0; e < 4; ++e)
          vv[e] = __uint_as_float((unsigned)uv[e] << 16) * invf[s2];
        __builtin_nontemporal_store(vv, (f32x4*)(abase + (size_t)row * WIN + Jb + c8 * 4));
      }
      // PV A-fragments: raw e, 16B contiguous per lane
      short8 af[2];
      #pragma unroll
      for (int fm = 0; fm < 2; ++fm) {
        int row = fm * 16 + l15;
        int sg = (g * 4 + l4) ^ (row & 7);
        af[fm] = *(const short8*)&JW[row * 64 + sg * 8];
      }
      __builtin_amdgcn_s_setprio(1);
      #pragma unroll
      for (int fm = 0; fm < 2; ++fm)
        #pragma unroll
        for (int nd = 0; nd < 4; ++nd)
          oacc[fm][nd] = __builtin_amdgcn_mfma_f32_16x16x32_bf16(af[fm], bv[nd], oacc[fm][nd], 0, 0, 0);
      __builtin_amdgcn_s_setprio(0);
    }
  }

  // ---------------- in-block O reduction in f32 via dead KP region; scale by invL
  __syncthreads();                              // all PV + staging drained
  float* OX = (float*)&KP[0][0][0];             // 32 KB = 4 waves x 2048 f32
  float* OW = OX + c * 2048;
  #pragma unroll
  for (int fm = 0; fm < 2; ++fm)
    #pragma unroll
    for (int nd = 0; nd < 4; ++nd)
      #pragma unroll
      for (int r = 0; r < 4; ++r)
        OW[(fm * 16 + l4 * 4 + r) * 64 + nd * 16 + l15] = oacc[fm][nd][r];
  __syncthreads();
  {
    int row = tid >> 3;
    int d0 = (tid & 7) * 8;
    float iv = invL[row];
    union { unsigned short u[8]; short8 v; } o;
    #pragma unroll
    for (int e = 0; e < 8; ++e) {
      int idx = row * 64 + d0 + e;
      float s = (OX[idx] + OX[2048 + idx] + OX[4096 + idx] + OX[6144 + idx]) * iv;
      o.u[e] = __bfloat16_as_ushort(__float2bfloat16(s));
    }
    *(short8*)&ao[(size_t)(i0 + row) * DM + h * HD + d0] = o.v;
  }
}

// ---------------------------------------------------------------- K4: proj GEMM -> d_out (f32)
__global__ __launch_bounds__(256) void k_gemm_proj(const bf16* __restrict__ A,
                                                   const bf16* __restrict__ B,
                                                   const float* __restrict__ bias,
                                                   float* __restrict__ out) {
  __shared__ bf16 As[128 * 64], Bs[128 * 64];
  const int tid = threadIdx.x, lane = tid & 63;
  const int wid = tid >> 6, wm = wid >> 1, wn = wid & 1;
  const int l15 = lane & 15, l4 = lane >> 4;
  const int m0 = blockIdx.x * 128, n0 = blockIdx.y * 128;
  f32x4 acc[4][4] = {};
  gemm_core(A, B, m0, n0, DM, tid, As, Bs, acc);
  #pragma unroll
  for (int im = 0; im < 4; ++im)
    #pragma unroll
    for (int in = 0; in < 4; ++in) {
      int col = n0 + wn * 64 + in * 16 + l15;
      float bval = bias[col];
      #pragma unroll
      for (int r = 0; r < 4; ++r) {
        int row = m0 + wm * 64 + im * 16 + l4 * 4 + r;
        out[(size_t)row * DM + col] = acc[im][in][r] + bval;
      }
    }
}

// ---------------------------------------------------------------- launch
extern "C" void kernel_launch(void* const* d_in, const int* in_sizes, int n_in,
                              void* d_out, int out_size, void* d_ws, size_t ws_size,
                              hipStream_t stream) {
  (void)in_sizes; (void)n_in; (void)out_size; (void)ws_size;
  const float* x  = (const float*)d_in[0];
  const float* wq = (const float*)d_in[1];
  const float* bq = (const float*)d_in[2];
  const float* wp = (const float*)d_in[3];
  const float* bp = (const float*)d_in[4];
  float* out  = (float*)d_out;
  float* attn = out + (size_t)SEQ * DM;

  char* ws = (char*)d_ws;
  bf16* xb    = (bf16*)(ws + (size_t) 0);          // 4 MB  x bf16
  bf16* wqb   = (bf16*)(ws + ((size_t)4  << 20));  // 6 MB  w_qkv bf16
  bf16* wpb   = (bf16*)(ws + ((size_t)10 << 20));  // 2 MB  w_proj bf16
  bf16* qarr  = (bf16*)(ws + ((size_t)12 << 20));  // 4 MB  q [h][i][d] (scale*log2e folded)
  bf16* karr  = (bf16*)(ws + ((size_t)16 << 20));  // 4 MB  k [h][j][d]
  bf16* vt    = (bf16*)(ws + ((size_t)24 << 20));  // 4 MB  vT [h][d][j] (qkv epilogue)
  bf16* ao    = (bf16*)(ws + ((size_t)28 << 20));  // 4 MB  attn-out rows [i][h*64+d]

  k_cvt<<<dim3(1024), dim3(256), 0, stream>>>(x, wq, wp, xb, wqb, wpb);
  k_gemm_qkv<<<dim3(16, 24), dim3(256), 0, stream>>>(xb, wqb, bq, qarr, karr, vt);
  k_attn<<<dim3(1024), dim3(256), 0, stream>>>(qarr, karr, vt, attn, ao);
  k_gemm_proj<<<dim3(16, 8), dim3(256), 0, stream>>>(ao, wpb, bp, out);
}

// Round 13
// 145.798 us; speedup vs baseline: 2.0898x; 1.0321x over previous
//
#include <hip/hip_runtime.h>
#include <hip/hip_bf16.h>

typedef __hip_bfloat16 bf16;
typedef __attribute__((ext_vector_type(8))) short short8;
typedef __attribute__((ext_vector_type(4))) float f32x4;
typedef __attribute__((ext_vector_type(4))) unsigned short ushort4v;

#define DEV static __device__ __forceinline__

static constexpr int SEQ = 2048;
static constexpr int DM  = 1024;
static constexpr int NH  = 16;
static constexpr int HD  = 64;
static constexpr int WIN = 2048;
static constexpr int PAD = 1024;   // WIN/2

// async global->LDS, 16B per lane; LDS dest = wave-uniform base + lane*16
DEV void async16(const void* g, void* l) {
  __builtin_amdgcn_global_load_lds(
      (__attribute__((address_space(1))) void*)(g),
      (__attribute__((address_space(3))) void*)(l), 16, 0, 0);
}

// ---------------------------------------------------------------- K0: f32 -> bf16 convert (x, w_qkv, w_proj)
__global__ __launch_bounds__(256) void k_cvt(const float* __restrict__ x,
                                             const float* __restrict__ wq,
                                             const float* __restrict__ wp,
                                             bf16* __restrict__ xb,
                                             bf16* __restrict__ wqb,
                                             bf16* __restrict__ wpb) {
  const int NX = SEQ * DM, NQ = 3 * DM * DM, NP = DM * DM;
  const int tot = (NX + NQ + NP) >> 2;
  const int stride = gridDim.x * 256;
  for (int i = blockIdx.x * 256 + threadIdx.x; i < tot; i += stride) {
    int e = i << 2;
    const float* s; bf16* d; int o;
    if (e < NX)            { s = x;  d = xb;  o = e; }
    else if (e < NX + NQ)  { s = wq; d = wqb; o = e - NX; }
    else                   { s = wp; d = wpb; o = e - NX - NQ; }
    float4 v = *(const float4*)(s + o);
    __align__(8) bf16 t4[4] = {__float2bfloat16(v.x), __float2bfloat16(v.y),
                               __float2bfloat16(v.z), __float2bfloat16(v.w)};
    *(uint2*)(d + o) = *(uint2*)t4;
  }
}

// ---------------------------------------------------------------- 64x128 GEMM core: C[m][n] = sum_k A[m][k]*B[n][k]
// 256 threads = 4 waves, each wave owns 64m x 32n (acc[4][2]); BK=64.
DEV void gemm_core64(const bf16* __restrict__ A, const bf16* __restrict__ B,
                     int m0, int n0, int K, int tid, bf16* As, bf16* Bs,
                     f32x4 (&acc)[4][2]) {
  const int lane = tid & 63, wid = tid >> 6;   // wid = n-group (0..3)
  const int l15 = lane & 15, l4 = lane >> 4;
  for (int k0 = 0; k0 < K; k0 += 64) {
    __syncthreads();
    #pragma unroll
    for (int it = 0; it < 2; ++it) {           // A: 64 rows
      int rb = it * 32 + wid * 8;
      int r  = rb + (lane >> 3);
      int c  = (lane & 7) * 8;
      async16(A + (size_t)(m0 + r) * K + k0 + c, As + rb * 64);
    }
    #pragma unroll
    for (int it = 0; it < 4; ++it) {           // B: 128 rows
      int rb = it * 32 + wid * 8;
      int r  = rb + (lane >> 3);
      int c  = (lane & 7) * 8;
      async16(B + (size_t)(n0 + r) * K + k0 + c, Bs + rb * 64);
    }
    asm volatile("s_waitcnt vmcnt(0)" ::: "memory");
    __syncthreads();
    #pragma unroll
    for (int kk = 0; kk < 2; ++kk) {
      short8 a[4], b[2];
      #pragma unroll
      for (int im = 0; im < 4; ++im)
        a[im] = *(const short8*)(As + (im * 16 + l15) * 64 + kk * 32 + l4 * 8);
      #pragma unroll
      for (int in = 0; in < 2; ++in)
        b[in] = *(const short8*)(Bs + (wid * 32 + in * 16 + l15) * 64 + kk * 32 + l4 * 8);
      #pragma unroll
      for (int im = 0; im < 4; ++im)
        #pragma unroll
        for (int in = 0; in < 2; ++in)
          acc[im][in] = __builtin_amdgcn_mfma_f32_16x16x32_bf16(a[im], b[in], acc[im][in], 0, 0, 0);
    }
  }
}

// ---------------------------------------------------------------- K1: qkv GEMM (64x128 tiles) + scatter to q/k/vT
__global__ __launch_bounds__(256) void k_gemm_qkv(const bf16* __restrict__ A,
                                                  const bf16* __restrict__ B,
                                                  const float* __restrict__ bias,
                                                  bf16* __restrict__ qo,
                                                  bf16* __restrict__ ko,
                                                  bf16* __restrict__ vt) {
  __shared__ bf16 As[64 * 64], Bs[128 * 64];
  const int tid = threadIdx.x, lane = tid & 63;
  const int wid = tid >> 6;
  const int l15 = lane & 15, l4 = lane >> 4;
  const int m0 = blockIdx.x * 64, n0 = blockIdx.y * 128;
  f32x4 acc[4][2] = {};
  gemm_core64(A, B, m0, n0, DM, tid, As, Bs, acc);
  #pragma unroll
  for (int im = 0; im < 4; ++im)
    #pragma unroll
    for (int in = 0; in < 2; ++in) {
      int col = n0 + wid * 32 + in * 16 + l15;
      float bval = bias[col];
      int t = col >> 10, h = (col >> 6) & 15, dd = col & 63;
      int row0 = m0 + im * 16 + l4 * 4;
      if (t == 2) {
        // v transposed directly: vT[h][dd][j], 4 consecutive j -> one 8B store
        __align__(8) bf16 t4[4];
        #pragma unroll
        for (int r = 0; r < 4; ++r)
          t4[r] = __float2bfloat16(acc[im][in][r] + bval);
        *(uint2*)&vt[((size_t)h * HD + dd) * SEQ + row0] = *(uint2*)t4;
      } else {
        #pragma unroll
        for (int r = 0; r < 4; ++r) {
          float v = acc[im][in][r] + bval;
          size_t idx = ((size_t)h * SEQ + row0 + r) * HD + dd;
          // q folded with hd^-0.5 * log2(e) so scores feed exp2 directly
          if (t == 0) qo[idx] = __float2bfloat16(v * 0.18033688011112042f);
          else        ko[idx] = __float2bfloat16(v);
        }
      }
    }
}

// ---------------------------------------------------------------- attn helpers
DEV void stage_kp(const bf16* kbase, int i0, int tt, int lane, bf16* dst) {
  #pragma unroll
  for (int it = 0; it < 4; ++it) {
    int r  = it * 8 + (lane >> 3);
    int cg = lane & 7;
    int jp = i0 + tt * 32 + r;                 // absolute j'
    int krow = jp - PAD;                       // clamp; pad handled analytically
    krow = krow < 0 ? 0 : (krow > SEQ - 1 ? SEQ - 1 : krow);
    int sc = (cg ^ (r & 7)) * 8;               // pre-swizzled global source
    async16(kbase + (size_t)krow * HD + sc, dst + it * 8 * 64);
  }
}

// LDS K -> MFMA, unswapped: sf[fm][fn]: col=j'(l15), row=i(l4*4+r)
DEV void qk_mfma_lds(const bf16* KPb, const short8 (&qf)[2][2], int l15, int l4,
                     f32x4 (&sf)[2][2]) {
  __builtin_amdgcn_s_setprio(1);
  #pragma unroll
  for (int kg = 0; kg < 2; ++kg) {
    short8 kfr[2];
    #pragma unroll
    for (int fn = 0; fn < 2; ++fn) {
      int jl = fn * 16 + l15;
      int pg = (kg * 4 + l4) ^ (jl & 7);
      kfr[fn] = *(const short8*)&KPb[jl * 64 + pg * 8];
    }
    #pragma unroll
    for (int fm = 0; fm < 2; ++fm)
      #pragma unroll
      for (int fn = 0; fn < 2; ++fn)
        sf[fm][fn] = __builtin_amdgcn_mfma_f32_16x16x32_bf16(qf[fm][kg], kfr[fn], sf[fm][fn], 0, 0, 0);
  }
  __builtin_amdgcn_s_setprio(0);
}

// swapped variant (phase 1): sf[fj][fi]: col=i(l15), row=j'(l4*4+r)
DEV void qk_mfma_lds_sw(const bf16* KPb, const short8 (&qf)[2][2], int l15, int l4,
                        f32x4 (&sf)[2][2]) {
  __builtin_amdgcn_s_setprio(1);
  #pragma unroll
  for (int kg = 0; kg < 2; ++kg) {
    short8 kfr[2];
    #pragma unroll
    for (int fj = 0; fj < 2; ++fj) {
      int jl = fj * 16 + l15;
      int pg = (kg * 4 + l4) ^ (jl & 7);
      kfr[fj] = *(const short8*)&KPb[jl * 64 + pg * 8];
    }
    #pragma unroll
    for (int fj = 0; fj < 2; ++fj)
      #pragma unroll
      for (int fi = 0; fi < 2; ++fi)
        sf[fj][fi] = __builtin_amdgcn_mfma_f32_16x16x32_bf16(kfr[fj], qf[fi][kg], sf[fj][fi], 0, 0, 0);
  }
  __builtin_amdgcn_s_setprio(0);
}

DEV int pad_lo(int i0) { int d = PAD - i0; return d <= 0 ? 0 : (d >> 5); }
DEV int pad_hi(int i0) { int t = ((PAD + SEQ - 1 - i0) >> 5) + 1; return t > 65 ? 65 : t; }

// ---------------------------------------------------------------- K2: merged attn (sum pass + normalize/flush/PV pass)
// block = (h, i0) via XCD-chunked swizzle; 4 chunk-waves.
__global__ __launch_bounds__(256) void k_attn(const bf16* __restrict__ q,
                                              const bf16* __restrict__ kkk,
                                              const bf16* __restrict__ vT,
                                              float* __restrict__ attn,
                                              bf16* __restrict__ ao) {
  // XCD-aware bijective swizzle (1024 % 8 == 0): each XCD gets contiguous work
  const int wgid = (blockIdx.x & 7) * 128 + (blockIdx.x >> 3);
  const int h  = wgid >> 6;
  const int i0 = (wgid & 63) << 5;
  const int tid = threadIdx.x;
  const int c = tid >> 6;                     // wave = chunk
  const int lane = tid & 63;
  const int l15 = lane & 15, l4 = lane >> 4;
  const int lo_g = pad_lo(i0), hi_g = pad_hi(i0);

  __shared__ bf16 KP[4][2][32 * 64];          // 32 KB; f32 O-exchange after PV
  __shared__ unsigned short JFB[4][32 * 64];  // 16 KB raw-e bf16 ring, 16B-group XOR swizzle
  __shared__ float sums[4][32];
  __shared__ float invL[32];

  short8 qf[2][2];
  #pragma unroll
  for (int fm = 0; fm < 2; ++fm)
    #pragma unroll
    for (int kg = 0; kg < 2; ++kg)
      qf[fm][kg] = *(const short8*)&q[((size_t)h * SEQ + i0 + fm * 16 + l15) * HD + kg * 32 + l4 * 8];

  const bf16* kbase = kkk + (size_t)h * SEQ * HD;
  const bf16* vbase = vT + (size_t)h * HD * SEQ;
  float* abase = attn + (size_t)(h * SEQ + i0) * WIN;

  // ---------------- phase 1: partial exp-sums (swapped QK)
  {
    constexpr int st[5] = {0, 16, 32, 48, 65};
    int lo = st[c] > lo_g ? st[c] : lo_g;
    int hi = st[c + 1] < hi_g ? st[c + 1] : hi_g;

    float psum[2] = {0.f, 0.f};
    if (lo < hi) {
      stage_kp(kbase, i0, lo, lane, KP[c][lo & 1]);
      for (int tt = lo; tt < hi; ++tt) {
        int nxt = (tt + 1 < hi) ? tt + 1 : tt;
        stage_kp(kbase, i0, nxt, lane, KP[c][(tt + 1) & 1]);
        asm volatile("s_waitcnt vmcnt(4)" ::: "memory");
        f32x4 sf[2][2] = {};
        qk_mfma_lds_sw(KP[c][tt & 1], qf, l15, l4, sf);
        const bool interior = (tt >= 1) && (tt <= 63) &&
                              (i0 + tt * 32 >= PAD) && (i0 + tt * 32 + 31 < PAD + SEQ);
        if (interior) {
          #pragma unroll
          for (int fj = 0; fj < 2; ++fj)
            #pragma unroll
            for (int r = 0; r < 4; ++r) {
              psum[0] += __builtin_amdgcn_exp2f(sf[fj][0][r]);
              psum[1] += __builtin_amdgcn_exp2f(sf[fj][1][r]);
            }
        } else {
          #pragma unroll
          for (int fj = 0; fj < 2; ++fj)
            #pragma unroll
            for (int r = 0; r < 4; ++r) {
              int jj = tt * 32 + fj * 16 + l4 * 4 + r;   // local j'
              int jp = i0 + jj;                          // absolute j'
              bool pad = (jp < PAD) || (jp >= PAD + SEQ);
              #pragma unroll
              for (int fi = 0; fi < 2; ++fi) {
                int iloc = fi * 16 + l15;
                float e = pad ? 1.0f : __builtin_amdgcn_exp2f(sf[fj][fi][r]);
                if ((unsigned)(jj - iloc) < (unsigned)WIN) psum[fi] += e;
              }
            }
        }
      }
    }
    float r0 = psum[0];
    r0 += __shfl_xor(r0, 16); r0 += __shfl_xor(r0, 32);
    float r1 = psum[1];
    r1 += __shfl_xor(r1, 16); r1 += __shfl_xor(r1, 32);
    if (lane < 32) {
      int i_abs = i0 + lane;
      float s = (lane < 16) ? r0 : r1;
      if (c == 0) {
        int cl = i0 + lo_g * 32 - i_abs; if (cl < 0) cl = 0;
        int cr = i_abs + WIN - (i0 + hi_g * 32); if (cr < 0) cr = 0;
        s += (float)(cl + cr);                  // analytic all-pad contribution
      }
      sums[c][lane] = s;
    }
  }
  __syncthreads();
  if (tid < 32)
    invL[tid] = __builtin_amdgcn_rcpf(sums[0][tid] + sums[1][tid] +
                                      sums[2][tid] + sums[3][tid]);
  __syncthreads();

  // per-lane flush inverses (row = s2*8 + (lane>>3))
  float invf[4];
  #pragma unroll
  for (int s2 = 0; s2 < 4; ++s2) invf[s2] = invL[s2 * 8 + (lane >> 3)];

  // ---------------- phase 2: recompute QK, raw-e rebin, normalized flush, PV
  const int c0 = c * 16, c1 = c0 + 16;
  unsigned short* JW = JFB[c];
  f32x4 oacc[2][4] = {};
  stage_kp(kbase, i0, c0, lane, KP[c][0]);     // c0 even -> buf 0
  for (int tt = c0; tt <= c1; ++tt) {
    short8 bv[4];
    if (tt > c0) {
      int jb = (tt - 1) * 32;
      #pragma unroll
      for (int nd = 0; nd < 4; ++nd)
        bv[nd] = *(const short8*)&vbase[(size_t)(nd * 16 + l15) * SEQ + jb + l4 * 8];
    }
    int nxt = (tt < c1) ? tt + 1 : tt;
    stage_kp(kbase, i0, nxt, lane, KP[c][(tt + 1) & 1]);
    // counted wait for stage(tt): younger = stores(t-1)[4]+bv[4]+stage(t+1)[4]
    if (tt == c0)          asm volatile("s_waitcnt vmcnt(4)" ::: "memory");
    else if (tt == c0 + 1) asm volatile("s_waitcnt vmcnt(8)" ::: "memory");
    else                   asm volatile("s_waitcnt vmcnt(12)" ::: "memory");

    const bool fp = (tt < lo_g) || (tt >= hi_g);   // all-pad tile: score==0 -> e=1
    f32x4 sf[2][2] = {};
    if (!fp) qk_mfma_lds(KP[c][tt & 1], qf, l15, l4, sf);

    // re-bin raw e (bf16) into j-aligned ring; 16B-group swizzle sg=(j6>>3)^(row&7)
    const bool allv = (i0 + tt * 32 >= PAD) && (i0 + tt * 32 + 31 < PAD + SEQ);
    #pragma unroll
    for (int fm = 0; fm < 2; ++fm)
      #pragma unroll
      for (int fn = 0; fn < 2; ++fn) {
        int J0 = tt * 32 + fn * 16 + l15;          // local j' (col)
        bool padc = fp || (!allv && ((i0 + J0 < PAD) || (i0 + J0 >= PAD + SEQ)));
        #pragma unroll
        for (int r = 0; r < 4; ++r) {
          int row = fm * 16 + l4 * 4 + r;          // local i
          float e = padc ? 1.0f : __builtin_amdgcn_exp2f(sf[fm][fn][r]);
          int j6 = (J0 - row) & 63;                // ring position
          int sg = (j6 >> 3) ^ (row & 7);
          JW[row * 64 + sg * 8 + (j6 & 7)] = __bfloat16_as_ushort(__float2bfloat16(e));
        }
      }

    if (tt > c0) {
      const int g = (tt - 1) & 1;                  // ring slot of completed j-tile
      const int Jb = (tt - 1) * 32;
      const int c8 = lane & 7;
      // flush: normalize raw e with invL at store time; full-128B-line stores
      #pragma unroll
      for (int s2 = 0; s2 < 4; ++s2) {
        int row = s2 * 8 + (lane >> 3);
        int sg = (g * 4 + (c8 >> 1)) ^ (row & 7);
        ushort4v uv = *(const ushort4v*)&JW[row * 64 + sg * 8 + (c8 & 1) * 4];
        f32x4 vv;
        #pragma unroll
        for (int e = 0; e < 4; ++e)
          vv[e] = __uint_as_float((unsigned)uv[e] << 16) * invf[s2];
        *(f32x4*)(abase + (size_t)row * WIN + Jb + c8 * 4) = vv;
      }
      // PV A-fragments: raw e, 16B contiguous per lane
      short8 af[2];
      #pragma unroll
      for (int fm = 0; fm < 2; ++fm) {
        int row = fm * 16 + l15;
        int sg = (g * 4 + l4) ^ (row & 7);
        af[fm] = *(const short8*)&JW[row * 64 + sg * 8];
      }
      __builtin_amdgcn_s_setprio(1);
      #pragma unroll
      for (int fm = 0; fm < 2; ++fm)
        #pragma unroll
        for (int nd = 0; nd < 4; ++nd)
          oacc[fm][nd] = __builtin_amdgcn_mfma_f32_16x16x32_bf16(af[fm], bv[nd], oacc[fm][nd], 0, 0, 0);
      __builtin_amdgcn_s_setprio(0);
    }
  }

  // ---------------- in-block O reduction in f32 via dead KP region; scale by invL
  __syncthreads();                              // all PV + staging drained
  float* OX = (float*)&KP[0][0][0];             // 32 KB = 4 waves x 2048 f32
  float* OW = OX + c * 2048;
  #pragma unroll
  for (int fm = 0; fm < 2; ++fm)
    #pragma unroll
    for (int nd = 0; nd < 4; ++nd)
      #pragma unroll
      for (int r = 0; r < 4; ++r)
        OW[(fm * 16 + l4 * 4 + r) * 64 + nd * 16 + l15] = oacc[fm][nd][r];
  __syncthreads();
  {
    int row = tid >> 3;
    int d0 = (tid & 7) * 8;
    float iv = invL[row];
    union { unsigned short u[8]; short8 v; } o;
    #pragma unroll
    for (int e = 0; e < 8; ++e) {
      int idx = row * 64 + d0 + e;
      float s = (OX[idx] + OX[2048 + idx] + OX[4096 + idx] + OX[6144 + idx]) * iv;
      o.u[e] = __bfloat16_as_ushort(__float2bfloat16(s));
    }
    *(short8*)&ao[(size_t)(i0 + row) * DM + h * HD + d0] = o.v;
  }
}

// ---------------------------------------------------------------- K4: proj GEMM (64x128 tiles) -> d_out (f32)
__global__ __launch_bounds__(256) void k_gemm_proj(const bf16* __restrict__ A,
                                                   const bf16* __restrict__ B,
                                                   const float* __restrict__ bias,
                                                   float* __restrict__ out) {
  __shared__ bf16 As[64 * 64], Bs[128 * 64];
  const int tid = threadIdx.x, lane = tid & 63;
  const int wid = tid >> 6;
  const int l15 = lane & 15, l4 = lane >> 4;
  const int m0 = blockIdx.x * 64, n0 = blockIdx.y * 128;
  f32x4 acc[4][2] = {};
  gemm_core64(A, B, m0, n0, DM, tid, As, Bs, acc);
  #pragma unroll
  for (int im = 0; im < 4; ++im)
    #pragma unroll
    for (int in = 0; in < 2; ++in) {
      int col = n0 + wid * 32 + in * 16 + l15;
      float bval = bias[col];
      #pragma unroll
      for (int r = 0; r < 4; ++r) {
        int row = m0 + im * 16 + l4 * 4 + r;
        out[(size_t)row * DM + col] = acc[im][in][r] + bval;
      }
    }
}

// ---------------------------------------------------------------- launch
extern "C" void kernel_launch(void* const* d_in, const int* in_sizes, int n_in,
                              void* d_out, int out_size, void* d_ws, size_t ws_size,
                              hipStream_t stream) {
  (void)in_sizes; (void)n_in; (void)out_size; (void)ws_size;
  const float* x  = (const float*)d_in[0];
  const float* wq = (const float*)d_in[1];
  const float* bq = (const float*)d_in[2];
  const float* wp = (const float*)d_in[3];
  const float* bp = (const float*)d_in[4];
  float* out  = (float*)d_out;
  float* attn = out + (size_t)SEQ * DM;

  char* ws = (char*)d_ws;
  bf16* xb    = (bf16*)(ws + (size_t) 0);          // 4 MB  x bf16
  bf16* wqb   = (bf16*)(ws + ((size_t)4  << 20));  // 6 MB  w_qkv bf16
  bf16* wpb   = (bf16*)(ws + ((size_t)10 << 20));  // 2 MB  w_proj bf16
  bf16* qarr  = (bf16*)(ws + ((size_t)12 << 20));  // 4 MB  q [h][i][d] (scale*log2e folded)
  bf16* karr  = (bf16*)(ws + ((size_t)16 << 20));  // 4 MB  k [h][j][d]
  bf16* vt    = (bf16*)(ws + ((size_t)24 << 20));  // 4 MB  vT [h][d][j] (qkv epilogue)
  bf16* ao    = (bf16*)(ws + ((size_t)28 << 20));  // 4 MB  attn-out rows [i][h*64+d]

  k_cvt<<<dim3(1024), dim3(256), 0, stream>>>(x, wq, wp, xb, wqb, wpb);
  k_gemm_qkv<<<dim3(32, 24), dim3(256), 0, stream>>>(xb, wqb, bq, qarr, karr, vt);
  k_attn<<<dim3(1024), dim3(256), 0, stream>>>(qarr, karr, vt, attn, ao);
  k_gemm_proj<<<dim3(32, 8), dim3(256), 0, stream>>>(ao, wpb, bp, out);
}